// Round 2
// baseline (774.613 us; speedup 1.0000x reference)
//
#include <hip/hip_runtime.h>
#include <hip/hip_bf16.h>

typedef unsigned int uint;
typedef unsigned short ushort;
typedef __bf16 bf16;
typedef __attribute__((ext_vector_type(8))) __bf16 bf16x8;
typedef __attribute__((ext_vector_type(4))) float floatx4;
typedef __attribute__((ext_vector_type(2))) float floatx2;

// ---- CSR build --------------------------------------------------------------
__global__ void k_init(int* cnt, int N) {
    int i = blockIdx.x * 256 + threadIdx.x;
    if (i < N) cnt[i] = 0;
}

__global__ void k_count(const int* __restrict__ ei, int* __restrict__ cnt, int E) {
    int e = blockIdx.x * 256 + threadIdx.x;
    if (e < E) atomicAdd(&cnt[ei[E + e]], 1);   // row 1 of edge_index = dst
}

// chunk = 1024 elements per block (256 threads x 4)
__global__ void k_scanA(const int* __restrict__ cnt, int* __restrict__ bsum, int N) {
    __shared__ int ws4[4];
    int t = threadIdx.x;
    int base = blockIdx.x * 1024 + t * 4;
    int s = 0;
#pragma unroll
    for (int i = 0; i < 4; i++) { int idx = base + i; if (idx < N) s += cnt[idx]; }
    int v = s;
    for (int off = 32; off > 0; off >>= 1) v += __shfl_down(v, off);
    if ((t & 63) == 0) ws4[t >> 6] = v;
    __syncthreads();
    if (t == 0) bsum[blockIdx.x] = ws4[0] + ws4[1] + ws4[2] + ws4[3];
}

__global__ void k_scanB(const int* __restrict__ bsum, int* __restrict__ boff, int NB) {
    __shared__ int lds[128];
    int t = threadIdx.x;
    int v = (t < NB) ? bsum[t] : 0;
    lds[t] = v;
    __syncthreads();
    for (int d2 = 1; d2 < 128; d2 <<= 1) {
        int x = (t >= d2) ? lds[t - d2] : 0;
        __syncthreads();
        lds[t] += x;
        __syncthreads();
    }
    if (t < NB) boff[t] = lds[t] - v;   // exclusive
}

__global__ void k_scanC(const int* __restrict__ cnt, const int* __restrict__ boff,
                        int* __restrict__ row_ptr, int* __restrict__ cursor,
                        float* __restrict__ inv, int N, int E) {
    __shared__ int wsum[4];
    int t = threadIdx.x, lane = t & 63, wid = t >> 6;
    int base = blockIdx.x * 1024 + t * 4;
    int c4[4]; int s = 0;
#pragma unroll
    for (int i = 0; i < 4; i++) { int idx = base + i; c4[i] = (idx < N) ? cnt[idx] : 0; s += c4[i]; }
    int v = s;
    for (int d2 = 1; d2 < 64; d2 <<= 1) { int x = __shfl_up(v, d2); if (lane >= d2) v += x; }
    if (lane == 63) wsum[wid] = v;
    __syncthreads();
    int woff = 0;
    for (int i = 0; i < wid; i++) woff += wsum[i];
    int run = boff[blockIdx.x] + woff + v - s;   // exclusive prefix for this thread
#pragma unroll
    for (int i = 0; i < 4; i++) {
        int idx = base + i;
        if (idx < N) {
            row_ptr[idx] = run;
            cursor[idx]  = run;
            inv[idx]     = rsqrtf((float)(c4[i] + 1));   // +1 self-loop
            run += c4[i];
        }
    }
    if (blockIdx.x == 0 && t == 0) row_ptr[N] = E;
}

__global__ void k_scatter(const int* __restrict__ ei, const float* __restrict__ inv,
                          int* __restrict__ cursor, int* __restrict__ colv,
                          float* __restrict__ normv, int E) {
    int e = blockIdx.x * 256 + threadIdx.x;
    if (e >= E) return;
    int s = ei[e], d = ei[E + e];
    int pos = atomicAdd(&cursor[d], 1);
    colv[pos]  = s;
    normv[pos] = inv[s] * inv[d];
}

// ---- weight prep: W fp32 [K][Nn] -> transposed bf16 split Wh/Wl [Nn][K] -----
__global__ void k_prepw(const float* __restrict__ W, bf16* __restrict__ Wh,
                        bf16* __restrict__ Wl, int K, int Nn) {
    int i = blockIdx.x * 256 + threadIdx.x;
    if (i < K * Nn) {
        int k = i / Nn, n = i % Nn;
        float w = W[(size_t)k * Nn + n];
        bf16 h = (bf16)w;
        Wh[(size_t)n * K + k] = h;
        Wl[(size_t)n * K + k] = (bf16)(w - (float)h);
    }
}

// ---- GEMM: Out[N x NOUT] = A[N x 128] @ W, bf16x3 split, fp32 acc -----------
// Block: 256 threads = 4 waves; 64 rows x 64 cols per block.
template <int NOUT, bool BIAS>
__global__ __launch_bounds__(256) void k_gemm3(const float* __restrict__ A,
                                               const bf16* __restrict__ Wh,
                                               const bf16* __restrict__ Wl,
                                               const float* __restrict__ bias,
                                               float* __restrict__ Out, int nRows) {
    constexpr int COLB = NOUT / 64;            // col blocks of 64
    __shared__ bf16 ldsH[64 * 136];            // +8 pad: 2-way bank alias (free)
    __shared__ bf16 ldsL[64 * 136];
    const int tid = threadIdx.x;
    const int blockRow = blockIdx.x / COLB;
    const int colBase  = (blockIdx.x % COLB) * 64;

    for (int i = tid; i < 2048; i += 256) {    // 2 arrays x 64 rows x 16 chunks
        int which = i >> 10, rem = i & 1023;
        int r = rem >> 4, c = rem & 15;
        const bf16* src = which ? Wl : Wh;
        bf16* dst = which ? ldsL : ldsH;
        *(bf16x8*)&dst[r * 136 + c * 8] =
            *(const bf16x8*)&src[(size_t)(colBase + r) * 128 + c * 8];
    }
    __syncthreads();

    const int w = tid >> 6, lane = tid & 63;
    const int q = lane >> 4, m = lane & 15;
    const int rowBase = blockRow * 64 + w * 16;
    int arow = rowBase + m; if (arow >= nRows) arow = nRows - 1;

    floatx4 acc[4];
#pragma unroll
    for (int i = 0; i < 4; i++) acc[i] = (floatx4)0.0f;

#pragma unroll
    for (int k0 = 0; k0 < 128; k0 += 32) {
        const float* ap = A + (size_t)arow * 128 + k0 + q * 8;
        float af[8];
        *(floatx4*)&af[0] = *(const floatx4*)ap;
        *(floatx4*)&af[4] = *(const floatx4*)(ap + 4);
        bf16x8 ah, al;
#pragma unroll
        for (int i = 0; i < 8; i++) {
            bf16 h = (bf16)af[i];
            ah[i] = h;
            al[i] = (bf16)(af[i] - (float)h);
        }
#pragma unroll
        for (int ct = 0; ct < 4; ++ct) {
            bf16x8 bh = *(const bf16x8*)&ldsH[(ct * 16 + m) * 136 + k0 + q * 8];
            bf16x8 bl = *(const bf16x8*)&ldsL[(ct * 16 + m) * 136 + k0 + q * 8];
            acc[ct] = __builtin_amdgcn_mfma_f32_16x16x32_bf16(ah, bh, acc[ct], 0, 0, 0);
            acc[ct] = __builtin_amdgcn_mfma_f32_16x16x32_bf16(al, bh, acc[ct], 0, 0, 0);
            acc[ct] = __builtin_amdgcn_mfma_f32_16x16x32_bf16(ah, bl, acc[ct], 0, 0, 0);
        }
    }
#pragma unroll
    for (int ct = 0; ct < 4; ++ct) {
        int col = colBase + ct * 16 + m;            // C/D: col = lane&15
        float bv = BIAS ? bias[col] : 0.0f;
#pragma unroll
        for (int r = 0; r < 4; ++r) {
            int orow = rowBase + q * 4 + r;         // C/D: row = quad*4 + reg
            if (orow < nRows)
                Out[(size_t)orow * NOUT + col] = acc[ct][r] + bv;
        }
    }
}

// ---- aggregation: hb[d] = act( sum_e norm*tb[src] + tb[d]/deg + bias ) ------
__global__ __launch_bounds__(256) void k_agg(const float* __restrict__ tb,
                                             const int* __restrict__ colv,
                                             const float* __restrict__ normv,
                                             const int* __restrict__ row_ptr,
                                             const float* __restrict__ inv,
                                             const float* __restrict__ bias,
                                             float* __restrict__ hb,
                                             int relu, int N) {
    int wid = threadIdx.x >> 6, lane = threadIdx.x & 63;
    int d = blockIdx.x * 4 + wid;    // one wave per node
    if (d >= N) return;
    int beg = row_ptr[d], end = row_ptr[d + 1];
    float isd = inv[d];
    float wself = isd * isd;         // inv_sqrt[d]^2 = 1/deg
    floatx2 p = *(const floatx2*)(tb + (size_t)d * 128 + lane * 2);
    float a0 = wself * p[0], a1 = wself * p[1];

    for (int e0 = beg; e0 < end; e0 += 64) {
        int me = e0 + lane;
        int sl = 0; float wl = 0.0f;
        if (me < end) { sl = colv[me]; wl = normv[me]; }   // coalesced batch load
        int cnt = end - e0; if (cnt > 64) cnt = 64;
        for (int j = 0; j < cnt; ++j) {
            int s   = __shfl(sl, j);
            float w = __shfl(wl, j);
            floatx2 pv = *(const floatx2*)(tb + (size_t)s * 128 + lane * 2);
            a0 += w * pv[0];
            a1 += w * pv[1];
        }
    }
    floatx2 bp = *(const floatx2*)(bias + lane * 2);
    a0 += bp[0]; a1 += bp[1];
    if (relu) { a0 = fmaxf(a0, 0.0f); a1 = fmaxf(a1, 0.0f); }
    floatx2 r; r[0] = a0; r[1] = a1;
    *(floatx2*)(hb + (size_t)d * 128 + lane * 2) = r;
}

// ---- host -------------------------------------------------------------------
extern "C" void kernel_launch(void* const* d_in, const int* in_sizes, int n_in,
                              void* d_out, int out_size, void* d_ws, size_t ws_size,
                              hipStream_t stream) {
    const int N = in_sizes[0] / 128;   // 100000
    const int E = in_sizes[1] / 2;     // 1600000

    const float* x    = (const float*)d_in[0];
    const int*   ei   = (const int*)d_in[1];
    const float* W1   = (const float*)d_in[2];
    const float* b1   = (const float*)d_in[3];
    const float* W2   = (const float*)d_in[4];
    const float* b2   = (const float*)d_in[5];
    const float* W3   = (const float*)d_in[6];
    const float* b3   = (const float*)d_in[7];
    const float* Wout = (const float*)d_in[8];
    const float* bout = (const float*)d_in[9];
    float* out = (float*)d_out;

    char* p = (char*)d_ws;
    auto alloc = [&](size_t bytes) -> void* {
        void* r = (void*)p;
        p += (bytes + 255) & ~(size_t)255;
        return r;
    };
    int*    cnt     = (int*)alloc((size_t)N * 4);
    int*    row_ptr = (int*)alloc(((size_t)N + 1) * 4);
    int*    cursor  = (int*)alloc((size_t)N * 4);
    float*  inv     = (float*)alloc((size_t)N * 4);
    int*    bsum    = (int*)alloc(128 * 4);
    int*    boff    = (int*)alloc(128 * 4);
    int*    colv    = (int*)alloc((size_t)E * 4);
    float*  normv   = (float*)alloc((size_t)E * 4);
    bf16*   Wh1     = (bf16*)alloc(128 * 128 * 2);
    bf16*   Wl1     = (bf16*)alloc(128 * 128 * 2);
    bf16*   Wh2     = (bf16*)alloc(128 * 128 * 2);
    bf16*   Wl2     = (bf16*)alloc(128 * 128 * 2);
    bf16*   Wh3     = (bf16*)alloc(128 * 128 * 2);
    bf16*   Wl3     = (bf16*)alloc(128 * 128 * 2);
    bf16*   Who     = (bf16*)alloc(64 * 128 * 2);
    bf16*   Wlo     = (bf16*)alloc(64 * 128 * 2);
    float*  hb      = (float*)alloc((size_t)N * 128 * 4);
    float*  tb      = (float*)alloc((size_t)N * 128 * 4);

    const int NB = (N + 1023) / 1024;          // 98 (<=128)
    const int gE = (E + 255) / 256;
    const int gN = (N + 255) / 256;
    const int rowBlocks = (N + 63) / 64;
    const int gAgg = (N + 3) / 4;

    // CSR build
    k_init<<<gN, 256, 0, stream>>>(cnt, N);
    k_count<<<gE, 256, 0, stream>>>(ei, cnt, E);
    k_scanA<<<NB, 256, 0, stream>>>(cnt, bsum, N);
    k_scanB<<<1, 128, 0, stream>>>(bsum, boff, NB);
    k_scanC<<<NB, 256, 0, stream>>>(cnt, boff, row_ptr, cursor, inv, N, E);
    k_scatter<<<gE, 256, 0, stream>>>(ei, inv, cursor, colv, normv, E);

    // weight prep (transpose + bf16 split)
    k_prepw<<<64, 256, 0, stream>>>(W1, Wh1, Wl1, 128, 128);
    k_prepw<<<64, 256, 0, stream>>>(W2, Wh2, Wl2, 128, 128);
    k_prepw<<<64, 256, 0, stream>>>(W3, Wh3, Wl3, 128, 128);
    k_prepw<<<32, 256, 0, stream>>>(Wout, Who, Wlo, 128, 64);

    // layer 1: t = x@W1 ; h = relu(agg(t)+b1)
    k_gemm3<128, false><<<rowBlocks * 2, 256, 0, stream>>>(x, Wh1, Wl1, nullptr, tb, N);
    k_agg<<<gAgg, 256, 0, stream>>>(tb, colv, normv, row_ptr, inv, b1, hb, 1, N);
    // layer 2
    k_gemm3<128, false><<<rowBlocks * 2, 256, 0, stream>>>(hb, Wh2, Wl2, nullptr, tb, N);
    k_agg<<<gAgg, 256, 0, stream>>>(tb, colv, normv, row_ptr, inv, b2, hb, 1, N);
    // layer 3 (no relu)
    k_gemm3<128, false><<<rowBlocks * 2, 256, 0, stream>>>(hb, Wh3, Wl3, nullptr, tb, N);
    k_agg<<<gAgg, 256, 0, stream>>>(tb, colv, normv, row_ptr, inv, b3, hb, 0, N);
    // output projection with bias
    k_gemm3<64, true><<<rowBlocks, 256, 0, stream>>>(hb, Who, Wlo, bout, out, N);
}

// Round 3
// 665.445 us; speedup vs baseline: 1.1641x; 1.1641x over previous
//
#include <hip/hip_runtime.h>

typedef unsigned int uint;
typedef _Float16 half_t;
typedef __attribute__((ext_vector_type(8))) _Float16 halfx8;
typedef __attribute__((ext_vector_type(2))) _Float16 halfx2;
typedef __attribute__((ext_vector_type(4))) float floatx4;
typedef __attribute__((ext_vector_type(2))) float floatx2;
typedef __attribute__((ext_vector_type(2))) int intx2;

// ---- CSR build --------------------------------------------------------------
__global__ void k_init(int* cnt, int N) {
    int i = blockIdx.x * 256 + threadIdx.x;
    if (i < N) cnt[i] = 0;
}

__global__ void k_count(const int* __restrict__ ei, int* __restrict__ cnt, int E) {
    int e = blockIdx.x * 256 + threadIdx.x;
    if (e < E) atomicAdd(&cnt[ei[E + e]], 1);   // row 1 of edge_index = dst
}

// chunk = 1024 elements per block (256 threads x 4)
__global__ void k_scanA(const int* __restrict__ cnt, int* __restrict__ bsum, int N) {
    __shared__ int ws4[4];
    int t = threadIdx.x;
    int base = blockIdx.x * 1024 + t * 4;
    int s = 0;
#pragma unroll
    for (int i = 0; i < 4; i++) { int idx = base + i; if (idx < N) s += cnt[idx]; }
    int v = s;
    for (int off = 32; off > 0; off >>= 1) v += __shfl_down(v, off);
    if ((t & 63) == 0) ws4[t >> 6] = v;
    __syncthreads();
    if (t == 0) bsum[blockIdx.x] = ws4[0] + ws4[1] + ws4[2] + ws4[3];
}

__global__ void k_scanB(const int* __restrict__ bsum, int* __restrict__ boff, int NB) {
    __shared__ int lds[128];
    int t = threadIdx.x;
    int v = (t < NB) ? bsum[t] : 0;
    lds[t] = v;
    __syncthreads();
    for (int d2 = 1; d2 < 128; d2 <<= 1) {
        int x = (t >= d2) ? lds[t - d2] : 0;
        __syncthreads();
        lds[t] += x;
        __syncthreads();
    }
    if (t < NB) boff[t] = lds[t] - v;   // exclusive
}

__global__ void k_scanC(const int* __restrict__ cnt, const int* __restrict__ boff,
                        int* __restrict__ row_ptr, int* __restrict__ cursor,
                        float* __restrict__ inv, int N, int E) {
    __shared__ int wsum[4];
    int t = threadIdx.x, lane = t & 63, wid = t >> 6;
    int base = blockIdx.x * 1024 + t * 4;
    int c4[4]; int s = 0;
#pragma unroll
    for (int i = 0; i < 4; i++) { int idx = base + i; c4[i] = (idx < N) ? cnt[idx] : 0; s += c4[i]; }
    int v = s;
    for (int d2 = 1; d2 < 64; d2 <<= 1) { int x = __shfl_up(v, d2); if (lane >= d2) v += x; }
    if (lane == 63) wsum[wid] = v;
    __syncthreads();
    int woff = 0;
    for (int i = 0; i < wid; i++) woff += wsum[i];
    int run = boff[blockIdx.x] + woff + v - s;   // exclusive prefix for this thread
#pragma unroll
    for (int i = 0; i < 4; i++) {
        int idx = base + i;
        if (idx < N) {
            row_ptr[idx] = run;
            cursor[idx]  = run;
            inv[idx]     = rsqrtf((float)(c4[i] + 1));   // +1 self-loop
            run += c4[i];
        }
    }
    if (blockIdx.x == 0 && t == 0) row_ptr[N] = E;
}

__global__ void k_scatter(const int* __restrict__ ei, const float* __restrict__ inv,
                          int* __restrict__ cursor, intx2* __restrict__ rec, int E) {
    int e = blockIdx.x * 256 + threadIdx.x;
    if (e >= E) return;
    int s = ei[e], d = ei[E + e];
    int pos = atomicAdd(&cursor[d], 1);
    intx2 r; r[0] = s; r[1] = __float_as_int(inv[s] * inv[d]);
    rec[pos] = r;                       // one 8B store instead of two 4B scatters
}

// ---- weight prep: W fp32 [K][Nn] -> transposed fp16 split Wh/Wl [Nn][K] -----
__global__ void k_prepw(const float* __restrict__ W, half_t* __restrict__ Wh,
                        half_t* __restrict__ Wl, int K, int Nn) {
    int i = blockIdx.x * 256 + threadIdx.x;
    if (i < K * Nn) {
        int k = i / Nn, n = i % Nn;
        float w = W[(size_t)k * Nn + n];
        half_t h = (half_t)w;
        Wh[(size_t)n * K + k] = h;
        Wl[(size_t)n * K + k] = (half_t)(w - (float)h);
    }
}

// ---- GEMM: Out[N x NOUT] = A[N x 128] @ W, fp16 MFMA, W=Wh+Wl, fp32 acc ----
// Block: 4 waves; each wave 32 rows x NOUT cols; block = 128 rows, A read once.
template <typename AT, typename OT, int NOUT, bool BIAS>
__global__ __launch_bounds__(256) void k_gemm(const AT* __restrict__ A,
                                              const half_t* __restrict__ Wh,
                                              const half_t* __restrict__ Wl,
                                              const float* __restrict__ bias,
                                              OT* __restrict__ Out, int nRows) {
    constexpr int CT = NOUT / 16;
    __shared__ __align__(16) half_t lds[2 * NOUT * 136];  // h then l; +8 pad

    const int tid = threadIdx.x;
    for (int i = tid; i < NOUT * 32; i += 256) {   // 2 arrays x NOUT rows x 16 chunks
        int which = (i >= NOUT * 16) ? 1 : 0;
        int rem = i - which * NOUT * 16;
        int r = rem >> 4, c = rem & 15;
        const half_t* src = which ? Wl : Wh;
        *(halfx8*)&lds[which * NOUT * 136 + r * 136 + c * 8] =
            *(const halfx8*)&src[(size_t)r * 128 + c * 8];
    }
    __syncthreads();

    const int w = tid >> 6, lane = tid & 63;
    const int q = lane >> 4, m = lane & 15;
    const int rowBase = blockIdx.x * 128 + w * 32;
    int arow[2];
#pragma unroll
    for (int rt = 0; rt < 2; ++rt) {
        int r = rowBase + rt * 16 + m;
        arow[rt] = (r < nRows) ? r : (nRows - 1);
    }

    floatx4 acc[2][CT];
#pragma unroll
    for (int rt = 0; rt < 2; ++rt)
#pragma unroll
        for (int ct = 0; ct < CT; ++ct) acc[rt][ct] = (floatx4)0.0f;

#pragma unroll
    for (int k0 = 0; k0 < 128; k0 += 32) {
        halfx8 a[2];
#pragma unroll
        for (int rt = 0; rt < 2; ++rt) {
            const AT* ap = A + (size_t)arow[rt] * 128 + k0 + q * 8;
            if constexpr (sizeof(AT) == 4) {
                floatx4 f0 = *(const floatx4*)ap;
                floatx4 f1 = *(const floatx4*)(ap + 4);
#pragma unroll
                for (int i = 0; i < 4; i++) { a[rt][i] = (half_t)f0[i]; a[rt][4 + i] = (half_t)f1[i]; }
            } else {
                a[rt] = *(const halfx8*)ap;
            }
        }
#pragma unroll
        for (int ct = 0; ct < CT; ++ct) {
            halfx8 bh = *(const halfx8*)&lds[(ct * 16 + m) * 136 + k0 + q * 8];
            halfx8 bl = *(const halfx8*)&lds[NOUT * 136 + (ct * 16 + m) * 136 + k0 + q * 8];
#pragma unroll
            for (int rt = 0; rt < 2; ++rt) {
                acc[rt][ct] = __builtin_amdgcn_mfma_f32_16x16x32_f16(a[rt], bh, acc[rt][ct], 0, 0, 0);
                acc[rt][ct] = __builtin_amdgcn_mfma_f32_16x16x32_f16(a[rt], bl, acc[rt][ct], 0, 0, 0);
            }
        }
    }
#pragma unroll
    for (int rt = 0; rt < 2; ++rt)
#pragma unroll
        for (int ct = 0; ct < CT; ++ct) {
            int col = ct * 16 + m;                      // C/D: col = lane&15
            float bv = BIAS ? bias[col] : 0.0f;
#pragma unroll
            for (int r = 0; r < 4; ++r) {
                int orow = rowBase + rt * 16 + q * 4 + r;   // C/D: row = quad*4 + reg
                if (orow < nRows)
                    Out[(size_t)orow * NOUT + col] = (OT)(acc[rt][ct][r] + bv);
            }
        }
}

// ---- aggregation: hb[d] = act( sum_e norm*tb[src] + tb[d]/deg + bias ) ------
__global__ __launch_bounds__(256) void k_agg(const half_t* __restrict__ tb,
                                             const intx2* __restrict__ rec,
                                             const int* __restrict__ row_ptr,
                                             const float* __restrict__ inv,
                                             const float* __restrict__ bias,
                                             half_t* __restrict__ hb,
                                             int relu, int N) {
    int wid = threadIdx.x >> 6, lane = threadIdx.x & 63;
    int d = blockIdx.x * 4 + wid;    // one wave per node
    if (d >= N) return;
    int beg = row_ptr[d], end = row_ptr[d + 1];
    float isd = inv[d];
    float wself = isd * isd;         // inv_sqrt[d]^2 = 1/deg
    halfx2 p = *(const halfx2*)(tb + (size_t)d * 128 + lane * 2);
    float a0 = wself * (float)p[0], a1 = wself * (float)p[1];

    for (int e0 = beg; e0 < end; e0 += 64) {
        int me = e0 + lane;
        int sl = 0; float wl = 0.0f;
        if (me < end) { intx2 r = rec[me]; sl = r[0]; wl = __int_as_float(r[1]); }
        int cnt = end - e0; if (cnt > 64) cnt = 64;
        for (int j = 0; j < cnt; ++j) {
            int s   = __shfl(sl, j);
            float w = __shfl(wl, j);
            halfx2 pv = *(const halfx2*)(tb + (size_t)s * 128 + lane * 2);
            a0 += w * (float)pv[0];
            a1 += w * (float)pv[1];
        }
    }
    floatx2 bp = *(const floatx2*)(bias + lane * 2);
    a0 += bp[0]; a1 += bp[1];
    if (relu) { a0 = fmaxf(a0, 0.0f); a1 = fmaxf(a1, 0.0f); }
    halfx2 r2; r2[0] = (half_t)a0; r2[1] = (half_t)a1;
    *(halfx2*)(hb + (size_t)d * 128 + lane * 2) = r2;
}

// ---- host -------------------------------------------------------------------
extern "C" void kernel_launch(void* const* d_in, const int* in_sizes, int n_in,
                              void* d_out, int out_size, void* d_ws, size_t ws_size,
                              hipStream_t stream) {
    const int N = in_sizes[0] / 128;   // 100000
    const int E = in_sizes[1] / 2;     // 1600000

    const float* x    = (const float*)d_in[0];
    const int*   ei   = (const int*)d_in[1];
    const float* W1   = (const float*)d_in[2];
    const float* b1   = (const float*)d_in[3];
    const float* W2   = (const float*)d_in[4];
    const float* b2   = (const float*)d_in[5];
    const float* W3   = (const float*)d_in[6];
    const float* b3   = (const float*)d_in[7];
    const float* Wout = (const float*)d_in[8];
    const float* bout = (const float*)d_in[9];
    float* out = (float*)d_out;

    char* p = (char*)d_ws;
    auto alloc = [&](size_t bytes) -> void* {
        void* r = (void*)p;
        p += (bytes + 255) & ~(size_t)255;
        return r;
    };
    int*    cnt     = (int*)alloc((size_t)N * 4);
    int*    row_ptr = (int*)alloc(((size_t)N + 1) * 4);
    int*    cursor  = (int*)alloc((size_t)N * 4);
    float*  inv     = (float*)alloc((size_t)N * 4);
    int*    bsum    = (int*)alloc(128 * 4);
    int*    boff    = (int*)alloc(128 * 4);
    intx2*  rec     = (intx2*)alloc((size_t)E * 8);
    half_t* Wh1     = (half_t*)alloc(128 * 128 * 2);
    half_t* Wl1     = (half_t*)alloc(128 * 128 * 2);
    half_t* Wh2     = (half_t*)alloc(128 * 128 * 2);
    half_t* Wl2     = (half_t*)alloc(128 * 128 * 2);
    half_t* Wh3     = (half_t*)alloc(128 * 128 * 2);
    half_t* Wl3     = (half_t*)alloc(128 * 128 * 2);
    half_t* Who     = (half_t*)alloc(64 * 128 * 2);
    half_t* Wlo     = (half_t*)alloc(64 * 128 * 2);
    half_t* hb      = (half_t*)alloc((size_t)N * 128 * 2);
    half_t* tb      = (half_t*)alloc((size_t)N * 128 * 2);

    const int NB = (N + 1023) / 1024;          // 98 (<=128)
    const int gE = (E + 255) / 256;
    const int gN = (N + 255) / 256;
    const int gGemm = (N + 127) / 128;
    const int gAgg = (N + 3) / 4;

    // CSR build
    k_init<<<gN, 256, 0, stream>>>(cnt, N);
    k_count<<<gE, 256, 0, stream>>>(ei, cnt, E);
    k_scanA<<<NB, 256, 0, stream>>>(cnt, bsum, N);
    k_scanB<<<1, 128, 0, stream>>>(bsum, boff, NB);
    k_scanC<<<NB, 256, 0, stream>>>(cnt, boff, row_ptr, cursor, inv, N, E);
    k_scatter<<<gE, 256, 0, stream>>>(ei, inv, cursor, rec, E);

    // weight prep (transpose + fp16 split)
    k_prepw<<<64, 256, 0, stream>>>(W1, Wh1, Wl1, 128, 128);
    k_prepw<<<64, 256, 0, stream>>>(W2, Wh2, Wl2, 128, 128);
    k_prepw<<<64, 256, 0, stream>>>(W3, Wh3, Wl3, 128, 128);
    k_prepw<<<32, 256, 0, stream>>>(Wout, Who, Wlo, 128, 64);

    // layer 1: t = x@W1 ; h = relu(agg(t)+b1)
    k_gemm<float, half_t, 128, false><<<gGemm, 256, 0, stream>>>(x, Wh1, Wl1, nullptr, tb, N);
    k_agg<<<gAgg, 256, 0, stream>>>(tb, rec, row_ptr, inv, b1, hb, 1, N);
    // layer 2
    k_gemm<half_t, half_t, 128, false><<<gGemm, 256, 0, stream>>>(hb, Wh2, Wl2, nullptr, tb, N);
    k_agg<<<gAgg, 256, 0, stream>>>(tb, rec, row_ptr, inv, b2, hb, 1, N);
    // layer 3 (no relu)
    k_gemm<half_t, half_t, 128, false><<<gGemm, 256, 0, stream>>>(hb, Wh3, Wl3, nullptr, tb, N);
    k_agg<<<gAgg, 256, 0, stream>>>(tb, rec, row_ptr, inv, b3, hb, 0, N);
    // output projection with bias (fp32 out)
    k_gemm<half_t, float, 64, true><<<gGemm, 256, 0, stream>>>(hb, Who, Wlo, bout, out, N);
}

// Round 4
// 504.311 us; speedup vs baseline: 1.5360x; 1.3195x over previous
//
#include <hip/hip_runtime.h>

typedef unsigned int uint;
typedef _Float16 half_t;
typedef __attribute__((ext_vector_type(8))) _Float16 halfx8;
typedef __attribute__((ext_vector_type(4))) float floatx4;
typedef __attribute__((ext_vector_type(2))) int intx2;

// ---- CSR build --------------------------------------------------------------
__global__ void k_init(int* cnt, int N) {
    int i = blockIdx.x * 256 + threadIdx.x;
    if (i < N) cnt[i] = 0;
}

__global__ void k_count(const int* __restrict__ ei, int* __restrict__ cnt, int E) {
    int e = blockIdx.x * 256 + threadIdx.x;
    if (e < E) atomicAdd(&cnt[ei[E + e]], 1);   // row 1 of edge_index = dst
}

__global__ void k_scanA(const int* __restrict__ cnt, int* __restrict__ bsum, int N) {
    __shared__ int ws4[4];
    int t = threadIdx.x;
    int base = blockIdx.x * 1024 + t * 4;
    int s = 0;
#pragma unroll
    for (int i = 0; i < 4; i++) { int idx = base + i; if (idx < N) s += cnt[idx]; }
    int v = s;
    for (int off = 32; off > 0; off >>= 1) v += __shfl_down(v, off);
    if ((t & 63) == 0) ws4[t >> 6] = v;
    __syncthreads();
    if (t == 0) bsum[blockIdx.x] = ws4[0] + ws4[1] + ws4[2] + ws4[3];
}

__global__ void k_scanB(const int* __restrict__ bsum, int* __restrict__ boff, int NB) {
    __shared__ int lds[128];
    int t = threadIdx.x;
    int v = (t < NB) ? bsum[t] : 0;
    lds[t] = v;
    __syncthreads();
    for (int d2 = 1; d2 < 128; d2 <<= 1) {
        int x = (t >= d2) ? lds[t - d2] : 0;
        __syncthreads();
        lds[t] += x;
        __syncthreads();
    }
    if (t < NB) boff[t] = lds[t] - v;   // exclusive
}

__global__ void k_scanC(const int* __restrict__ cnt, const int* __restrict__ boff,
                        int* __restrict__ row_ptr, int* __restrict__ cursor,
                        float* __restrict__ inv, int N, int E) {
    __shared__ int wsum[4];
    int t = threadIdx.x, lane = t & 63, wid = t >> 6;
    int base = blockIdx.x * 1024 + t * 4;
    int c4[4]; int s = 0;
#pragma unroll
    for (int i = 0; i < 4; i++) { int idx = base + i; c4[i] = (idx < N) ? cnt[idx] : 0; s += c4[i]; }
    int v = s;
    for (int d2 = 1; d2 < 64; d2 <<= 1) { int x = __shfl_up(v, d2); if (lane >= d2) v += x; }
    if (lane == 63) wsum[wid] = v;
    __syncthreads();
    int woff = 0;
    for (int i = 0; i < wid; i++) woff += wsum[i];
    int run = boff[blockIdx.x] + woff + v - s;
#pragma unroll
    for (int i = 0; i < 4; i++) {
        int idx = base + i;
        if (idx < N) {
            row_ptr[idx] = run;
            cursor[idx]  = run;
            inv[idx]     = rsqrtf((float)(c4[i] + 1));   // +1 self-loop
            run += c4[i];
        }
    }
    if (blockIdx.x == 0 && t == 0) row_ptr[N] = E;
}

__global__ void k_scatter(const int* __restrict__ ei, const float* __restrict__ inv,
                          int* __restrict__ cursor, intx2* __restrict__ rec, int E) {
    int e = blockIdx.x * 256 + threadIdx.x;
    if (e >= E) return;
    int s = ei[e], d = ei[E + e];
    int pos = atomicAdd(&cursor[d], 1);
    intx2 r; r[0] = s; r[1] = __float_as_int(inv[s] * inv[d]);
    rec[pos] = r;
}

// ---- compose Wc = W3 @ Wout [128x64], bc = b3 @ Wout + bout -----------------
__global__ void k_compose(const float* __restrict__ W3, const float* __restrict__ Wout,
                          const float* __restrict__ b3, const float* __restrict__ bout,
                          float* __restrict__ Wc, float* __restrict__ bc) {
    int idx = blockIdx.x * 256 + threadIdx.x;
    if (idx < 128 * 64) {
        int i = idx >> 6, j = idx & 63;
        float s = 0.0f;
        for (int k = 0; k < 128; k++) s += W3[i * 128 + k] * Wout[k * 64 + j];
        Wc[idx] = s;
    } else if (idx < 128 * 64 + 64) {
        int j = idx - 128 * 64;
        float s = bout[j];
        for (int k = 0; k < 128; k++) s += b3[k] * Wout[k * 64 + j];
        bc[j] = s;
    }
}

// ---- weight prep: W fp32 [K][Nn] -> transposed fp16 split Wh/Wl [Nn][K] -----
__global__ void k_prepw(const float* __restrict__ W, half_t* __restrict__ Wh,
                        half_t* __restrict__ Wl, int K, int Nn) {
    int i = blockIdx.x * 256 + threadIdx.x;
    if (i < K * Nn) {
        int k = i / Nn, n = i % Nn;
        float w = W[(size_t)k * Nn + n];
        half_t h = (half_t)w;
        Wh[(size_t)n * K + k] = h;
        Wl[(size_t)n * K + k] = (half_t)(w - (float)h);
    }
}

// ---- GEMM: Out[N x NOUT] = A[N x 128] @ (Wh+Wl), fp16 MFMA, fp32 acc --------
// Two passes over one LDS buffer (Wh then Wl); A-fragments cached in registers.
template <typename AT, int NOUT>
__global__ __launch_bounds__(256) void k_gemm(const AT* __restrict__ A,
                                              const half_t* __restrict__ Wh,
                                              const half_t* __restrict__ Wl,
                                              half_t* __restrict__ Out, int nRows) {
    constexpr int CT = NOUT / 16;
    __shared__ __align__(16) half_t lds[NOUT * 136];   // +8 pad

    const int tid = threadIdx.x;
    for (int i = tid; i < NOUT * 16; i += 256) {
        int r = i >> 4, c = i & 15;
        *(halfx8*)&lds[r * 136 + c * 8] = *(const halfx8*)&Wh[(size_t)r * 128 + c * 8];
    }
    __syncthreads();

    const int w = tid >> 6, lane = tid & 63;
    const int q = lane >> 4, m = lane & 15;
    const int rowBase = blockIdx.x * 128 + w * 32;
    int arow[2];
#pragma unroll
    for (int rt = 0; rt < 2; ++rt) {
        int r = rowBase + rt * 16 + m;
        arow[rt] = (r < nRows) ? r : (nRows - 1);
    }

    floatx4 acc[2][CT];
#pragma unroll
    for (int rt = 0; rt < 2; ++rt)
#pragma unroll
        for (int ct = 0; ct < CT; ++ct) acc[rt][ct] = (floatx4)0.0f;

    halfx8 a[2][4];   // cached A fragments: 2 row-tiles x 4 k-steps
#pragma unroll
    for (int kk = 0; kk < 4; ++kk) {
#pragma unroll
        for (int rt = 0; rt < 2; ++rt) {
            const AT* ap = A + (size_t)arow[rt] * 128 + kk * 32 + q * 8;
            if constexpr (sizeof(AT) == 4) {
                floatx4 f0 = *(const floatx4*)ap;
                floatx4 f1 = *(const floatx4*)(ap + 4);
#pragma unroll
                for (int i = 0; i < 4; i++) { a[rt][kk][i] = (half_t)f0[i]; a[rt][kk][4 + i] = (half_t)f1[i]; }
            } else {
                a[rt][kk] = *(const halfx8*)ap;
            }
        }
#pragma unroll
        for (int ct = 0; ct < CT; ++ct) {
            halfx8 bh = *(const halfx8*)&lds[(ct * 16 + m) * 136 + kk * 32 + q * 8];
#pragma unroll
            for (int rt = 0; rt < 2; ++rt)
                acc[rt][ct] = __builtin_amdgcn_mfma_f32_16x16x32_f16(a[rt][kk], bh, acc[rt][ct], 0, 0, 0);
        }
    }
    __syncthreads();   // all waves done reading Wh
    for (int i = tid; i < NOUT * 16; i += 256) {
        int r = i >> 4, c = i & 15;
        *(halfx8*)&lds[r * 136 + c * 8] = *(const halfx8*)&Wl[(size_t)r * 128 + c * 8];
    }
    __syncthreads();
#pragma unroll
    for (int kk = 0; kk < 4; ++kk)
#pragma unroll
        for (int ct = 0; ct < CT; ++ct) {
            halfx8 bl = *(const halfx8*)&lds[(ct * 16 + m) * 136 + kk * 32 + q * 8];
#pragma unroll
            for (int rt = 0; rt < 2; ++rt)
                acc[rt][ct] = __builtin_amdgcn_mfma_f32_16x16x32_f16(a[rt][kk], bl, acc[rt][ct], 0, 0, 0);
        }

#pragma unroll
    for (int rt = 0; rt < 2; ++rt)
#pragma unroll
        for (int ct = 0; ct < CT; ++ct) {
            int col = ct * 16 + m;                      // C/D: col = lane&15
#pragma unroll
            for (int r = 0; r < 4; ++r) {
                int orow = rowBase + rt * 16 + q * 4 + r;   // C/D: row = quad*4 + reg
                if (orow < nRows)
                    Out[(size_t)orow * NOUT + col] = (half_t)acc[rt][ct][r];
            }
        }
}

// ---- aggregation: out[d] = act( sum_e norm*tb[src] + tb[d]/deg + bias ) -----
// Lane holds 8 channels (halfx8 = 16B); L = CH/8 lanes per row; G = 64/L edges
// per wave-load. 4 loads issued back-to-back -> 4x MLP. Butterfly-reduce groups.
template <int CH, typename OT, bool RELU>
__global__ __launch_bounds__(256) void k_agg(const half_t* __restrict__ tb,
                                             const intx2* __restrict__ rec,
                                             const int* __restrict__ row_ptr,
                                             const float* __restrict__ inv,
                                             const float* __restrict__ bias,
                                             OT* __restrict__ out, int N) {
    constexpr int L = CH / 8;     // lanes per row (16 or 8)
    constexpr int G = 64 / L;     // edges per wave-load (4 or 8)
    int wid = threadIdx.x >> 6, lane = threadIdx.x & 63;
    int d = blockIdx.x * 4 + wid;
    if (d >= N) return;
    int beg = row_ptr[d], end = row_ptr[d + 1];
    int grp = lane / L;
    int choff = (lane % L) * 8;
    float isd = inv[d];
    float ws0 = (grp == 0) ? isd * isd : 0.0f;   // self term counted once

    halfx8 pself = *(const halfx8*)(tb + (size_t)d * CH + choff);
    float af[8];
#pragma unroll
    for (int c = 0; c < 8; c++) af[c] = ws0 * (float)pself[c];

    for (int e0 = beg; e0 < end; e0 += 64) {
        int me = e0 + lane;
        int sl = 0; float wl = 0.0f;
        if (me < end) { intx2 r = rec[me]; sl = r[0]; wl = __int_as_float(r[1]); }
        int cnt = end - e0; if (cnt > 64) cnt = 64;
        for (int j = 0; j < cnt; j += 4 * G) {
            int s4[4]; float w4[4];
#pragma unroll
            for (int u = 0; u < 4; u++) {
                int idx = j + u * G + grp;          // always < 64; dead lanes have w=0
                s4[u] = __shfl(sl, idx);
                w4[u] = __shfl(wl, idx);
            }
            halfx8 pv[4];
#pragma unroll
            for (int u = 0; u < 4; u++)
                pv[u] = *(const halfx8*)(tb + (size_t)s4[u] * CH + choff);
#pragma unroll
            for (int u = 0; u < 4; u++)
#pragma unroll
                for (int c = 0; c < 8; c++)
                    af[c] += w4[u] * (float)pv[u][c];
        }
    }
    // reduce across edge-groups (lanes with same lane%L)
#pragma unroll
    for (int msk = L; msk < 64; msk <<= 1)
#pragma unroll
        for (int c = 0; c < 8; c++)
            af[c] += __shfl_xor(af[c], msk);

    if (lane < L) {
        int ch = lane * 8;
        floatx4 b0 = *(const floatx4*)(bias + ch);
        floatx4 b1 = *(const floatx4*)(bias + ch + 4);
#pragma unroll
        for (int c = 0; c < 8; c++) {
            af[c] += (c < 4) ? b0[c] : b1[c - 4];
            if (RELU) af[c] = fmaxf(af[c], 0.0f);
        }
        if constexpr (sizeof(OT) == 2) {
            halfx8 o;
#pragma unroll
            for (int c = 0; c < 8; c++) o[c] = (half_t)af[c];
            *(halfx8*)((half_t*)out + (size_t)d * CH + ch) = o;
        } else {
            floatx4 o0, o1;
#pragma unroll
            for (int c = 0; c < 4; c++) { o0[c] = af[c]; o1[c] = af[c + 4]; }
            *(floatx4*)((float*)out + (size_t)d * CH + ch) = o0;
            *(floatx4*)((float*)out + (size_t)d * CH + ch + 4) = o1;
        }
    }
}

// ---- host -------------------------------------------------------------------
extern "C" void kernel_launch(void* const* d_in, const int* in_sizes, int n_in,
                              void* d_out, int out_size, void* d_ws, size_t ws_size,
                              hipStream_t stream) {
    const int N = in_sizes[0] / 128;   // 100000
    const int E = in_sizes[1] / 2;     // 1600000

    const float* x    = (const float*)d_in[0];
    const int*   ei   = (const int*)d_in[1];
    const float* W1   = (const float*)d_in[2];
    const float* b1   = (const float*)d_in[3];
    const float* W2   = (const float*)d_in[4];
    const float* b2   = (const float*)d_in[5];
    const float* W3   = (const float*)d_in[6];
    const float* b3   = (const float*)d_in[7];
    const float* Wout = (const float*)d_in[8];
    const float* bout = (const float*)d_in[9];
    float* out = (float*)d_out;

    char* p = (char*)d_ws;
    auto alloc = [&](size_t bytes) -> void* {
        void* r = (void*)p;
        p += (bytes + 255) & ~(size_t)255;
        return r;
    };
    int*    cnt     = (int*)alloc((size_t)N * 4);
    int*    row_ptr = (int*)alloc(((size_t)N + 1) * 4);
    int*    cursor  = (int*)alloc((size_t)N * 4);
    float*  inv     = (float*)alloc((size_t)N * 4);
    int*    bsum    = (int*)alloc(128 * 4);
    int*    boff    = (int*)alloc(128 * 4);
    intx2*  rec     = (intx2*)alloc((size_t)E * 8);
    float*  Wc      = (float*)alloc(128 * 64 * 4);
    float*  bc      = (float*)alloc(64 * 4);
    half_t* Wh1     = (half_t*)alloc(128 * 128 * 2);
    half_t* Wl1     = (half_t*)alloc(128 * 128 * 2);
    half_t* Wh2     = (half_t*)alloc(128 * 128 * 2);
    half_t* Wl2     = (half_t*)alloc(128 * 128 * 2);
    half_t* Whc     = (half_t*)alloc(64 * 128 * 2);
    half_t* Wlc     = (half_t*)alloc(64 * 128 * 2);
    half_t* hb      = (half_t*)alloc((size_t)N * 128 * 2);
    half_t* tb      = (half_t*)alloc((size_t)N * 128 * 2);

    const int NB = (N + 1023) / 1024;
    const int gE = (E + 255) / 256;
    const int gN = (N + 255) / 256;
    const int gGemm = (N + 127) / 128;
    const int gAgg = (N + 3) / 4;

    // CSR build
    k_init<<<gN, 256, 0, stream>>>(cnt, N);
    k_count<<<gE, 256, 0, stream>>>(ei, cnt, E);
    k_scanA<<<NB, 256, 0, stream>>>(cnt, bsum, N);
    k_scanB<<<1, 128, 0, stream>>>(bsum, boff, NB);
    k_scanC<<<NB, 256, 0, stream>>>(cnt, boff, row_ptr, cursor, inv, N, E);
    k_scatter<<<gE, 256, 0, stream>>>(ei, inv, cursor, rec, E);

    // weight prep
    k_compose<<<33, 256, 0, stream>>>(W3, Wout, b3, bout, Wc, bc);
    k_prepw<<<64, 256, 0, stream>>>(W1, Wh1, Wl1, 128, 128);
    k_prepw<<<64, 256, 0, stream>>>(W2, Wh2, Wl2, 128, 128);
    k_prepw<<<32, 256, 0, stream>>>(Wc, Whc, Wlc, 128, 64);

    // layer 1
    k_gemm<float, 128><<<gGemm, 256, 0, stream>>>(x, Wh1, Wl1, tb, N);
    k_agg<128, half_t, true><<<gAgg, 256, 0, stream>>>(tb, rec, row_ptr, inv, b1, hb, N);
    // layer 2
    k_gemm<half_t, 128><<<gGemm, 256, 0, stream>>>(hb, Wh2, Wl2, tb, N);
    k_agg<128, half_t, true><<<gAgg, 256, 0, stream>>>(tb, rec, row_ptr, inv, b2, hb, N);
    // layer 3 fused with output projection: out = agg(h @ (W3@Wout)) + bc
    k_gemm<half_t, 64><<<gGemm, 256, 0, stream>>>(hb, Whc, Wlc, tb, N);
    k_agg<64, float, false><<<gAgg, 256, 0, stream>>>(tb, rec, row_ptr, inv, bc, out, N);
}